// Round 11
// baseline (152.757 us; speedup 1.0000x reference)
//
#include <hip/hip_runtime.h>

typedef __attribute__((ext_vector_type(8))) __bf16 bf16x8;
typedef __attribute__((ext_vector_type(4))) __bf16 bf16x4;
typedef __attribute__((ext_vector_type(4))) float f32x4;

#define N_SAMP 256
#define DIM    2048
#define NCENT  32000
#define INV_T  14.285714285714285714f   // 1 / 0.07
#define NWG    500                       // 250 n-tiles x 2 m-tiles, 256 thr each

// ---------------- kernel 1: row-normalize feats -> bf16; also zero d_acc ----------------
__global__ __launch_bounds__(256) void norm_kernel(const float* __restrict__ feats,
                                                   __bf16* __restrict__ fnorm,
                                                   float* __restrict__ d_acc) {
    int row = blockIdx.x;
    int tid = threadIdx.x;
    if (row < 16) d_acc[row * 256 + tid] = 0.f;   // zero 8 slots x 512 floats
    const float* src = feats + (size_t)row * DIM;
    float4 v0 = reinterpret_cast<const float4*>(src)[2 * tid];
    float4 v1 = reinterpret_cast<const float4*>(src)[2 * tid + 1];
    float ss = v0.x * v0.x + v0.y * v0.y + v0.z * v0.z + v0.w * v0.w
             + v1.x * v1.x + v1.y * v1.y + v1.z * v1.z + v1.w * v1.w;
    #pragma unroll
    for (int off = 1; off < 64; off <<= 1) ss += __shfl_xor(ss, off, 64);
    __shared__ float wsum[4];
    if ((tid & 63) == 0) wsum[tid >> 6] = ss;
    __syncthreads();
    float inv = 1.0f / sqrtf(wsum[0] + wsum[1] + wsum[2] + wsum[3]);
    bf16x8 o;
    o[0] = (__bf16)(v0.x * inv); o[1] = (__bf16)(v0.y * inv);
    o[2] = (__bf16)(v0.z * inv); o[3] = (__bf16)(v0.w * inv);
    o[4] = (__bf16)(v1.x * inv); o[5] = (__bf16)(v1.y * inv);
    o[6] = (__bf16)(v1.z * inv); o[7] = (__bf16)(v1.w * inv);
    *reinterpret_cast<bf16x8*>(fnorm + (size_t)row * DIM + tid * 8) = o;
}

// ------------- kernel 2: 128x128 tile, 4 waves, wave tile 64x64 -------------
// 500 blocks x 256 threads. BK=32. A+B staged regs -> XOR-swizzled LDS,
// depth-2 named sets, raw s_barrier + lgkmcnt(0)-only drain (vmcnt counted).
// 4 waves (2m x 2n) halve LDS read-amplification vs 8 thin waves; 64 KB total
// LDS -> 2 blocks/CU co-resident to cover barrier gaps.
__global__ __launch_bounds__(256, 2) void sims_kernel(
    const __bf16* __restrict__ fnorm, const float* __restrict__ centers,
    const int* __restrict__ labels, const int* __restrict__ camids,
    float* __restrict__ d_acc, float* __restrict__ d_own)
{
    __shared__ __align__(16) char sA[2][8192];   // 128 rows x 32 bf16 (64 B)
    __shared__ __align__(16) char sB[2][8192];

    const int tid  = threadIdx.x;
    const int wave = tid >> 6;
    const int lane = tid & 63;
    const int l15  = lane & 15;
    const int lhi  = lane >> 4;

    // bijective XCD swizzle (nwg=500: q=62, r=4); pairs (n, m=0/1) per XCD
    const int d   = blockIdx.x;
    const int xcd = d & 7, loc = d >> 3;
    const int lid = (xcd < 4 ? xcd * 63 : 252 + (xcd - 4) * 62) + loc;
    const int nb  = lid >> 1;     // 0..249 center tile (128 centers)
    const int mb  = lid & 1;      // 0..1   sample tile (128 samples)
    const int cbase = nb * 128;

    const int wr = (wave >> 1) * 64;    // wave rows within 128-row tile
    const int wc = (wave & 1) * 64;     // wave cols within 128-col tile

    f32x4 acc[4][4] = {};

    const float4* bsrc = reinterpret_cast<const float4*>(centers);
    const uint4*  asrc = reinterpret_cast<const uint4*>(fnorm);

    // B: 128 rows x 8 float4/step = 1024 -> 4/thread. A: 128 x 4 uint4 = 512 -> 2/thread.
    auto issue = [&](int step, float4 (&b)[4], uint4 (&a)[2]) {
        #pragma unroll
        for (int q = 0; q < 4; ++q) {
            int f = q * 256 + tid;
            int row = f >> 3, pos = f & 7;
            b[q] = bsrc[(size_t)(cbase + row) * 512 + step * 8 + pos];
        }
        #pragma unroll
        for (int q = 0; q < 2; ++q) {
            int f = q * 256 + tid;
            int row = f >> 2, pos = f & 3;
            a[q] = asrc[(size_t)(mb * 128 + row) * 256 + step * 4 + pos];
        }
    };
    auto wrbuf = [&](int buf, const float4 (&b)[4], const uint4 (&a)[2]) {
        #pragma unroll
        for (int q = 0; q < 4; ++q) {
            int f = q * 256 + tid;
            int row = f >> 3, pos = f & 7;
            int adr = (row * 64 + pos * 8) ^ ((row & 7) << 4);
            bf16x4 o;
            o[0] = (__bf16)b[q].x; o[1] = (__bf16)b[q].y;
            o[2] = (__bf16)b[q].z; o[3] = (__bf16)b[q].w;
            *reinterpret_cast<uint2*>(&sB[buf][adr]) = __builtin_bit_cast(uint2, o);
        }
        #pragma unroll
        for (int q = 0; q < 2; ++q) {
            int f = q * 256 + tid;
            int row = f >> 2, pos = f & 3;
            int adr = (row * 64 + pos * 16) ^ ((row & 7) << 4);
            *reinterpret_cast<uint4*>(&sA[buf][adr]) = a[q];
        }
    };
    auto compute = [&](int buf) {
        bf16x8 af[4], bf[4];
        #pragma unroll
        for (int mi = 0; mi < 4; ++mi) {
            int row = wr + mi * 16 + l15;
            int adr = (row * 64 + lhi * 16) ^ ((row & 7) << 4);
            af[mi] = *reinterpret_cast<const bf16x8*>(&sA[buf][adr]);
        }
        #pragma unroll
        for (int ni = 0; ni < 4; ++ni) {
            int row = wc + ni * 16 + l15;
            int adr = (row * 64 + lhi * 16) ^ ((row & 7) << 4);
            bf[ni] = *reinterpret_cast<const bf16x8*>(&sB[buf][adr]);
        }
        #pragma unroll
        for (int mi = 0; mi < 4; ++mi)
            #pragma unroll
            for (int ni = 0; ni < 4; ++ni)
                acc[mi][ni] = __builtin_amdgcn_mfma_f32_16x16x32_bf16(
                    af[mi], bf[ni], acc[mi][ni], 0, 0, 0);
    };
    #define BAR() do { asm volatile("s_waitcnt lgkmcnt(0)" ::: "memory"); \
                       __builtin_amdgcn_s_barrier(); } while (0)

    float4 bSA[4], bSB[4];
    uint4  aSA[2], aSB[2];

    issue(0, bSA, aSA);
    issue(1, bSB, aSB);
    wrbuf(0, bSA, aSA);
    BAR();
    for (int t = 0; t < 64; t += 2) {
        if (t + 2 < 64) issue(t + 2, bSA, aSA);
        compute(0);
        wrbuf(1, bSB, aSB);              // waits only set B; set A stays in flight
        BAR();
        if (t + 3 < 64) issue(t + 3, bSB, aSB);
        compute(1);
        if (t + 2 < 64) {
            wrbuf(0, bSA, aSA);
            BAR();
        }
    }

    // ---- epilogue: exp + masks + per-sample partial denominators ----
    float* slot = d_acc + (d & 7) * 512;
    #pragma unroll
    for (int mi = 0; mi < 4; ++mi) {
        #pragma unroll
        for (int r = 0; r < 4; ++r) {
            int i   = mb * 128 + wr + mi * 16 + lhi * 4 + r;
            int lab = labels[i], cam = camids[i];
            int oidx = lab * 8 + cam;
            float pi = 0.f, pj = 0.f;
            #pragma unroll
            for (int ni = 0; ni < 4; ++ni) {
                int c = cbase + wc + ni * 16 + l15;
                float s = acc[mi][ni][r] * INV_T;
                float e = __expf(s);
                if ((l15 & 7) == cam) pi += e;          // c % 8 == cam
                bool ol = ((c >> 3) == lab);
                bool hard = (!ol) && (c < ((c < lab * 8) ? 50 : 58));
                if (ol || hard) pj += e;
                if (c == oidx) d_own[i] = s;
            }
            #pragma unroll
            for (int off = 1; off < 16; off <<= 1) {
                pi += __shfl_xor(pi, off, 64);
                pj += __shfl_xor(pj, off, 64);
            }
            if (l15 == 0) {
                atomicAdd(&slot[i], pi);
                atomicAdd(&slot[N_SAMP + i], pj);
            }
        }
    }
}

// ---------------- kernel 3: finalize (segment means + output) ----------------
__global__ __launch_bounds__(256) void finalize_kernel(
    const float* __restrict__ d_acc, const float* __restrict__ d_own,
    const int* __restrict__ labels, const int* __restrict__ camids,
    float* __restrict__ out, int out_size)
{
    __shared__ int s_lab[N_SAMP], s_cam[N_SAMP];
    __shared__ float wsum[8];
    int tid = threadIdx.x;
    s_lab[tid] = labels[tid];
    s_cam[tid] = camids[tid];
    __syncthreads();
    int myl = s_lab[tid], myc = s_cam[tid];
    int nl = 0, nc = 0;
    for (int j = 0; j < N_SAMP; ++j) {
        nl += (s_lab[j] == myl);
        nc += (s_cam[j] == myc);
    }
    float di = 0.f, dj = 0.f;
    #pragma unroll
    for (int s = 0; s < 8; ++s) {
        di += d_acc[s * 512 + tid];
        dj += d_acc[s * 512 + 256 + tid];
    }
    float own = d_own[tid];
    float li = own - logf(di);
    float lj = own - logf(dj);
    float a = li / (float)nc;   // sum_i loss_i / n_cam == sum over cams of per-cam mean
    float b = lj / (float)nl;
    #pragma unroll
    for (int off = 1; off < 64; off <<= 1) {
        a += __shfl_xor(a, off, 64);
        b += __shfl_xor(b, off, 64);
    }
    if ((tid & 63) == 0) { wsum[tid >> 6] = a; wsum[4 + (tid >> 6)] = b; }
    __syncthreads();
    if (tid == 0) {
        float sa = wsum[0] + wsum[1] + wsum[2] + wsum[3];
        float sb = wsum[4] + wsum[5] + wsum[6] + wsum[7];
        out[0] = -sa;
        if (out_size > 1) out[1] = -0.5f * sb;   // LAMDA = 0.5
    }
}

extern "C" void kernel_launch(void* const* d_in, const int* in_sizes, int n_in,
                              void* d_out, int out_size, void* d_ws, size_t ws_size,
                              hipStream_t stream) {
    const float* feats   = (const float*)d_in[0];
    const float* centers = (const float*)d_in[1];
    const int*   labels  = (const int*)d_in[2];
    const int*   camids  = (const int*)d_in[3];
    float* out = (float*)d_out;

    __bf16* fnorm = (__bf16*)d_ws;
    float* d_acc  = (float*)((char*)d_ws + (size_t)N_SAMP * DIM * sizeof(__bf16));
    float* d_own  = d_acc + 8 * 2 * N_SAMP;

    norm_kernel<<<N_SAMP, 256, 0, stream>>>(feats, fnorm, d_acc);
    sims_kernel<<<NWG, 256, 0, stream>>>(fnorm, centers, labels, camids, d_acc, d_own);
    finalize_kernel<<<1, 256, 0, stream>>>(d_acc, d_own, labels, camids, out, out_size);
}

// Round 12
// 130.707 us; speedup vs baseline: 1.1687x; 1.1687x over previous
//
#include <hip/hip_runtime.h>

typedef __attribute__((ext_vector_type(8))) __bf16 bf16x8;
typedef __attribute__((ext_vector_type(4))) float f32x4;

#define N_SAMP 256
#define DIM    2048
#define NCENT  32000
#define INV_T  14.285714285714285714f   // 1 / 0.07
#define NWG    250                       // one 256x128 tile per block
#define NTILE  64                        // K / BK = 2048 / 32

// Swizzled element address within a 16KB (256-row) or 8KB (128-row) K-tile:
// byte = (row>>1)*128 + 16*( ((row&1)*4 + c8) ^ ((row>>1)&7) )  [+ (k&7)*2]
// Reads (16 lanes, rows r0..r0+15, fixed c8): 8 slots x 2 lanes = free.

// ---- kernel 1: normalize feats -> bf16, PRE-SWIZZLED per 32-k tile; zero d_acc+ticket ----
__global__ __launch_bounds__(256) void norm_kernel(const float* __restrict__ feats,
                                                   char* __restrict__ fnorm_sw,
                                                   float* __restrict__ d_acc,
                                                   int* __restrict__ ticket) {
    int row = blockIdx.x;
    int tid = threadIdx.x;
    if (row < 16) d_acc[row * 256 + tid] = 0.f;   // zero 8 slots x 512 floats
    if (row == 16 && tid == 0) *ticket = 0;
    const float* src = feats + (size_t)row * DIM;
    float4 v0 = reinterpret_cast<const float4*>(src)[2 * tid];
    float4 v1 = reinterpret_cast<const float4*>(src)[2 * tid + 1];
    float ss = v0.x * v0.x + v0.y * v0.y + v0.z * v0.z + v0.w * v0.w
             + v1.x * v1.x + v1.y * v1.y + v1.z * v1.z + v1.w * v1.w;
    #pragma unroll
    for (int off = 1; off < 64; off <<= 1) ss += __shfl_xor(ss, off, 64);
    __shared__ float wsum[4];
    if ((tid & 63) == 0) wsum[tid >> 6] = ss;
    __syncthreads();
    float inv = 1.0f / sqrtf(wsum[0] + wsum[1] + wsum[2] + wsum[3]);
    bf16x8 o;
    o[0] = (__bf16)(v0.x * inv); o[1] = (__bf16)(v0.y * inv);
    o[2] = (__bf16)(v0.z * inv); o[3] = (__bf16)(v0.w * inv);
    o[4] = (__bf16)(v1.x * inv); o[5] = (__bf16)(v1.y * inv);
    o[6] = (__bf16)(v1.z * inv); o[7] = (__bf16)(v1.w * inv);
    // k = tid*8 .. +7 -> tile = tid>>2, c8 = tid&3
    int tile = tid >> 2, c8 = tid & 3;
    int pair = row >> 1;
    int slot = (((row & 1) << 2) | c8) ^ (pair & 7);
    *reinterpret_cast<bf16x8*>(fnorm_sw + (size_t)tile * 16384 + pair * 128 + slot * 16) = o;
}

// ---- kernel 2: 256x128 tile, BK=32, A via global_load_lds, counted vmcnt, fused finalize ----
__global__ __launch_bounds__(512, 2) void sims_kernel(
    const char* __restrict__ fnorm_sw, const float* __restrict__ centers,
    const int* __restrict__ labels, const int* __restrict__ camids,
    float* __restrict__ d_acc, float* __restrict__ d_own,
    int* __restrict__ ticket, float* __restrict__ out, int out_size)
{
    __shared__ __align__(16) char sA[2][16384];  // 256 rows x 32 bf16, swizzled image
    __shared__ __align__(16) char sB[3][8192];   // 128 rows x 32 bf16, swizzled image

    const int tid  = threadIdx.x;
    const int wave = tid >> 6;
    const int lane = tid & 63;
    const int l15  = lane & 15;
    const int lhi  = lane >> 4;

    const int nb    = blockIdx.x;        // 0..249
    const int cbase = nb * 128;

    const int wr = (wave >> 1) * 64;     // wave rows in 256
    const int wc = (wave & 1) * 64;      // wave cols in 128

    f32x4 acc[4][4] = {};

    const float4* bsrc = reinterpret_cast<const float4*>(centers);

    // B staging map: thread -> physical 16B slot tid; inverse-swizzle to logical (row,c8)
    const int bP = tid >> 3, bs = tid & 7;
    const int bu = bs ^ (bP & 7);
    const int brow = 2 * bP + (bu >> 2);
    const int bc8  = bu & 3;
    const size_t bbase = (size_t)(cbase + brow) * 512 + bc8 * 2;

    auto issueB = [&](int T, float4& f0, float4& f1) {
        f0 = bsrc[bbase + T * 8];
        f1 = bsrc[bbase + T * 8 + 1];
    };
    auto wrbufB = [&](int buf, const float4& f0, const float4& f1) {
        bf16x8 o;
        o[0] = (__bf16)f0.x; o[1] = (__bf16)f0.y; o[2] = (__bf16)f0.z; o[3] = (__bf16)f0.w;
        o[4] = (__bf16)f1.x; o[5] = (__bf16)f1.y; o[6] = (__bf16)f1.z; o[7] = (__bf16)f1.w;
        *reinterpret_cast<bf16x8*>(&sB[buf][tid * 16]) = o;   // linear: conflict-free
    };
    auto aLds = [&](int T, int buf) {   // 16 KB linear DMA copy (pre-swizzled source)
        const char* src = fnorm_sw + (size_t)T * 16384 + (wave * 2) * 1024 + lane * 16;
        __builtin_amdgcn_global_load_lds((const unsigned int*)src,
                                         (unsigned int*)&sA[buf][(wave * 2) * 1024], 16, 0, 0);
        __builtin_amdgcn_global_load_lds((const unsigned int*)(src + 1024),
                                         (unsigned int*)&sA[buf][(wave * 2 + 1) * 1024], 16, 0, 0);
    };
    auto compute = [&](int bufA, int bufB) {
        bf16x8 af[4], bf[4];
        #pragma unroll
        for (int mi = 0; mi < 4; ++mi) {
            int row = wr + mi * 16 + l15, pair = row >> 1;
            int slot = (((row & 1) << 2) | lhi) ^ (pair & 7);
            af[mi] = *reinterpret_cast<const bf16x8*>(&sA[bufA][pair * 128 + slot * 16]);
        }
        #pragma unroll
        for (int ni = 0; ni < 4; ++ni) {
            int row = wc + ni * 16 + l15, pair = row >> 1;
            int slot = (((row & 1) << 2) | lhi) ^ (pair & 7);
            bf[ni] = *reinterpret_cast<const bf16x8*>(&sB[bufB][pair * 128 + slot * 16]);
        }
        __builtin_amdgcn_s_setprio(1);
        #pragma unroll
        for (int mi = 0; mi < 4; ++mi)
            #pragma unroll
            for (int ni = 0; ni < 4; ++ni)
                acc[mi][ni] = __builtin_amdgcn_mfma_f32_16x16x32_bf16(
                    af[mi], bf[ni], acc[mi][ni], 0, 0, 0);
        __builtin_amdgcn_s_setprio(0);
    };

    float4 b0S0, b1S0, b0S1, b1S1;   // B(k) lives in set k&1

    // prologue
    issueB(0, b0S0, b1S0);
    issueB(1, b0S1, b1S1);
    aLds(0, 0);
    wrbufB(0, b0S0, b1S0);
    asm volatile("s_waitcnt vmcnt(0)" ::: "memory");
    asm volatile("s_waitcnt lgkmcnt(0)" ::: "memory");
    __builtin_amdgcn_s_barrier();

    #pragma unroll
    for (int t = 0; t < NTILE; ++t) {
        const int cur = t & 1;
        if (t + 1 < NTILE) aLds(t + 1, cur ^ 1);
        if (t + 2 < NTILE) {
            if (((t + 2) & 1) == 0) issueB(t + 2, b0S0, b1S0);
            else                    issueB(t + 2, b0S1, b1S1);
        }
        compute(cur, t % 3);
        if (t + 1 < NTILE) {
            if (((t + 1) & 1) == 0) wrbufB((t + 1) % 3, b0S0, b1S0);
            else                    wrbufB((t + 1) % 3, b0S1, b1S1);
            if (t + 2 < NTILE) asm volatile("s_waitcnt vmcnt(2)" ::: "memory");
            else               asm volatile("s_waitcnt vmcnt(0)" ::: "memory");
            asm volatile("s_waitcnt lgkmcnt(0)" ::: "memory");
            __builtin_amdgcn_s_barrier();
        }
    }

    // ---- epilogue: exp + masks + per-sample partial denominators ----
    float* slot_acc = d_acc + (nb & 7) * 512;
    #pragma unroll
    for (int mi = 0; mi < 4; ++mi) {
        #pragma unroll
        for (int r = 0; r < 4; ++r) {
            int i   = wr + mi * 16 + lhi * 4 + r;
            int lab = labels[i], cam = camids[i];
            int oidx = lab * 8 + cam;
            float pi = 0.f, pj = 0.f;
            #pragma unroll
            for (int ni = 0; ni < 4; ++ni) {
                int c = cbase + wc + ni * 16 + l15;
                float s = acc[mi][ni][r] * INV_T;
                float e = __expf(s);
                if ((l15 & 7) == cam) pi += e;          // c % 8 == cam
                bool ol = ((c >> 3) == lab);
                bool hard = (!ol) && (c < ((c < lab * 8) ? 50 : 58));
                if (ol || hard) pj += e;
                if (c == oidx) d_own[i] = s;
            }
            #pragma unroll
            for (int off = 1; off < 16; off <<= 1) {
                pi += __shfl_xor(pi, off, 64);
                pj += __shfl_xor(pj, off, 64);
            }
            if (l15 == 0) {
                atomicAdd(&slot_acc[i], pi);
                atomicAdd(&slot_acc[N_SAMP + i], pj);
            }
        }
    }

    // ---- fused finalize: last block computes the two losses ----
    __threadfence();
    __syncthreads();
    __shared__ int s_last;
    if (tid == 0) s_last = (atomicAdd(ticket, 1) == NWG - 1) ? 1 : 0;
    __syncthreads();
    if (s_last) {
        __threadfence();
        int* s_lab = (int*)&sB[0][0];
        int* s_cam = s_lab + 256;
        float* wsum = (float*)(s_cam + 256);
        if (tid < 256) { s_lab[tid] = labels[tid]; s_cam[tid] = camids[tid]; }
        __syncthreads();
        float a = 0.f, b = 0.f;
        if (tid < 256) {
            int myl = s_lab[tid], myc = s_cam[tid];
            int nl = 0, nc = 0;
            for (int j = 0; j < 256; ++j) {
                nl += (s_lab[j] == myl);
                nc += (s_cam[j] == myc);
            }
            float di = 0.f, dj = 0.f;
            #pragma unroll
            for (int s = 0; s < 8; ++s) {
                di += d_acc[s * 512 + tid];
                dj += d_acc[s * 512 + 256 + tid];
            }
            float own = d_own[tid];
            a = (own - logf(di)) / (float)nc;
            b = (own - logf(dj)) / (float)nl;
        }
        #pragma unroll
        for (int off = 1; off < 64; off <<= 1) {
            a += __shfl_xor(a, off, 64);
            b += __shfl_xor(b, off, 64);
        }
        if ((tid & 63) == 0) { wsum[tid >> 6] = a; wsum[8 + (tid >> 6)] = b; }
        __syncthreads();
        if (tid == 0) {
            float sa = wsum[0] + wsum[1] + wsum[2] + wsum[3]
                     + wsum[4] + wsum[5] + wsum[6] + wsum[7];
            float sb = wsum[8] + wsum[9] + wsum[10] + wsum[11]
                     + wsum[12] + wsum[13] + wsum[14] + wsum[15];
            out[0] = -sa;
            if (out_size > 1) out[1] = -0.5f * sb;   // LAMDA = 0.5
        }
    }
}

extern "C" void kernel_launch(void* const* d_in, const int* in_sizes, int n_in,
                              void* d_out, int out_size, void* d_ws, size_t ws_size,
                              hipStream_t stream) {
    const float* feats   = (const float*)d_in[0];
    const float* centers = (const float*)d_in[1];
    const int*   labels  = (const int*)d_in[2];
    const int*   camids  = (const int*)d_in[3];
    float* out = (float*)d_out;

    char*  fnorm_sw = (char*)d_ws;                                   // 1 MB swizzled
    float* d_acc    = (float*)((char*)d_ws + (size_t)1048576);       // 8 slots x 512
    float* d_own    = d_acc + 8 * 2 * N_SAMP;                        // 256
    int*   ticket   = (int*)(d_own + N_SAMP);

    norm_kernel<<<N_SAMP, 256, 0, stream>>>(feats, fnorm_sw, d_acc, ticket);
    sims_kernel<<<NWG, 512, 0, stream>>>(fnorm_sw, centers, labels, camids,
                                         d_acc, d_own, ticket, out, out_size);
}

// Round 13
// 89.549 us; speedup vs baseline: 1.7059x; 1.4596x over previous
//
#include <hip/hip_runtime.h>

typedef __attribute__((ext_vector_type(8))) __bf16 bf16x8;
typedef __attribute__((ext_vector_type(4))) float f32x4;

#define N_SAMP 256
#define DIM    2048
#define NCENT  32000
#define INV_T  14.285714285714285714f   // 1 / 0.07
#define NWG    250                       // one 256x128 tile per block
#define NTILE  64                        // K / BK = 2048 / 32

// A is pre-packed in MFMA-fragment order by norm_kernel:
//   block (tile t, group g) = 1 KB: lane l holds rows g*16+(l&15), k = t*32+(l>>4)*8..+7
// B LDS tile (8 KB per buffer): linear ds_write at tid*16; swizzled read
//   row,c8 -> byte = (row>>1)*128 + 16*((((row&1)<<2)|c8) ^ ((row>>1)&7))   [R12: 0 conflicts]

// ---- kernel 1: normalize feats -> bf16 fragment-packed; zero d_acc ----
__global__ __launch_bounds__(256) void norm_kernel(const float* __restrict__ feats,
                                                   char* __restrict__ fnorm_pk,
                                                   float* __restrict__ d_acc) {
    int row = blockIdx.x;
    int tid = threadIdx.x;
    if (row < 16) d_acc[row * 256 + tid] = 0.f;   // zero 8 slots x 512 floats
    const float* src = feats + (size_t)row * DIM;
    float4 v0 = reinterpret_cast<const float4*>(src)[2 * tid];
    float4 v1 = reinterpret_cast<const float4*>(src)[2 * tid + 1];
    float ss = v0.x * v0.x + v0.y * v0.y + v0.z * v0.z + v0.w * v0.w
             + v1.x * v1.x + v1.y * v1.y + v1.z * v1.z + v1.w * v1.w;
    #pragma unroll
    for (int off = 1; off < 64; off <<= 1) ss += __shfl_xor(ss, off, 64);
    __shared__ float wsum[4];
    if ((tid & 63) == 0) wsum[tid >> 6] = ss;
    __syncthreads();
    float inv = 1.0f / sqrtf(wsum[0] + wsum[1] + wsum[2] + wsum[3]);
    bf16x8 o;
    o[0] = (__bf16)(v0.x * inv); o[1] = (__bf16)(v0.y * inv);
    o[2] = (__bf16)(v0.z * inv); o[3] = (__bf16)(v0.w * inv);
    o[4] = (__bf16)(v1.x * inv); o[5] = (__bf16)(v1.y * inv);
    o[6] = (__bf16)(v1.z * inv); o[7] = (__bf16)(v1.w * inv);
    // k = tid*8..+7: tile = tid>>2, ksub = tid&3; lane = (row&15) | (ksub<<4)
    int tile = tid >> 2, ksub = tid & 3;
    int grp  = row >> 4;
    int lane = (row & 15) | (ksub << 4);
    *reinterpret_cast<bf16x8*>(fnorm_pk
        + ((size_t)tile * 16 + grp) * 1024 + lane * 16) = o;
}

// ---- kernel 2: 256x128 tile, BK=32; A direct from packed global, B via LDS ----
// 250 blocks x 512 threads (8 waves = 4m x 2n; wave tile 64x64, acc 4x4).
// Depth-2 named sets for both A-frags and B-staging regs; rolled loop;
// raw s_barrier + lgkmcnt(0)-only drain (compiler manages vmcnt deps).
__global__ __launch_bounds__(512, 2) void sims_kernel(
    const char* __restrict__ fnorm_pk, const float* __restrict__ centers,
    const int* __restrict__ labels, const int* __restrict__ camids,
    float* __restrict__ d_acc, float* __restrict__ d_own)
{
    __shared__ __align__(16) char sB[2][8192];   // 128 rows x 32 bf16, swizzled image

    const int tid  = threadIdx.x;
    const int wave = tid >> 6;
    const int lane = tid & 63;
    const int l15  = lane & 15;
    const int lhi  = lane >> 4;

    const int nb    = blockIdx.x;        // 0..249
    const int cbase = nb * 128;

    const int wr = (wave >> 1) * 64;     // wave rows in 256 (4 m-groups)
    const int wc = (wave & 1) * 64;      // wave cols in 128 (2 n-halves)

    f32x4 acc[4][4] = {};

    const float4* bsrc = reinterpret_cast<const float4*>(centers);
    const char*   apk  = fnorm_pk + ((size_t)(wave >> 1) * 4) * 1024 + lane * 16;

    // B staging: thread -> physical 16B slot tid; inverse-swizzle to logical (row,c8)
    const int bP = tid >> 3, bs = tid & 7;
    const int bu = bs ^ (bP & 7);
    const int brow = 2 * bP + (bu >> 2);
    const int bc8  = bu & 3;
    const size_t bbase = (size_t)(cbase + brow) * 512 + bc8 * 2;

    auto issueB = [&](int T, float4& f0, float4& f1) {
        f0 = bsrc[bbase + T * 8];
        f1 = bsrc[bbase + T * 8 + 1];
    };
    auto wrbufB = [&](int buf, const float4& f0, const float4& f1) {
        bf16x8 o;
        o[0] = (__bf16)f0.x; o[1] = (__bf16)f0.y; o[2] = (__bf16)f0.z; o[3] = (__bf16)f0.w;
        o[4] = (__bf16)f1.x; o[5] = (__bf16)f1.y; o[6] = (__bf16)f1.z; o[7] = (__bf16)f1.w;
        *reinterpret_cast<bf16x8*>(&sB[buf][tid * 16]) = o;   // linear: conflict-free
    };
    auto issueA = [&](int T, bf16x8 (&af)[4]) {
        const char* p = apk + (size_t)T * 16384;   // 16 groups x 1 KB per K-tile
        af[0] = *reinterpret_cast<const bf16x8*>(p);
        af[1] = *reinterpret_cast<const bf16x8*>(p + 1024);
        af[2] = *reinterpret_cast<const bf16x8*>(p + 2048);
        af[3] = *reinterpret_cast<const bf16x8*>(p + 3072);
    };
    auto compute = [&](int buf, const bf16x8 (&af)[4]) {
        bf16x8 bf[4];
        #pragma unroll
        for (int ni = 0; ni < 4; ++ni) {
            int row = wc + ni * 16 + l15, pair = row >> 1;
            int slot = (((row & 1) << 2) | lhi) ^ (pair & 7);
            bf[ni] = *reinterpret_cast<const bf16x8*>(&sB[buf][pair * 128 + slot * 16]);
        }
        #pragma unroll
        for (int mi = 0; mi < 4; ++mi)
            #pragma unroll
            for (int ni = 0; ni < 4; ++ni)
                acc[mi][ni] = __builtin_amdgcn_mfma_f32_16x16x32_bf16(
                    af[mi], bf[ni], acc[mi][ni], 0, 0, 0);
    };
    #define BAR() do { asm volatile("s_waitcnt lgkmcnt(0)" ::: "memory"); \
                       __builtin_amdgcn_s_barrier(); } while (0)

    float4 b0S0, b1S0, b0S1, b1S1;
    bf16x8 afA[4], afB[4];

    issueB(0, b0S0, b1S0);
    issueB(1, b0S1, b1S1);
    issueA(0, afA);
    wrbufB(0, b0S0, b1S0);
    BAR();
    for (int t = 0; t < NTILE; t += 2) {
        if (t + 2 < NTILE) issueB(t + 2, b0S0, b1S0);
        issueA(t + 1, afB);
        compute(0, afA);
        wrbufB(1, b0S1, b1S1);           // dep-waits only its own B regs
        BAR();
        if (t + 3 < NTILE) issueB(t + 3, b0S1, b1S1);
        if (t + 2 < NTILE) issueA(t + 2, afA);
        compute(1, afB);
        if (t + 2 < NTILE) {
            wrbufB(0, b0S0, b1S0);
            BAR();
        }
    }

    // ---- epilogue: exp + masks + per-sample partial denominators ----
    float* slot_acc = d_acc + (nb & 7) * 512;
    #pragma unroll
    for (int mi = 0; mi < 4; ++mi) {
        #pragma unroll
        for (int r = 0; r < 4; ++r) {
            int i   = wr + mi * 16 + lhi * 4 + r;
            int lab = labels[i], cam = camids[i];
            int oidx = lab * 8 + cam;
            float pi = 0.f, pj = 0.f;
            #pragma unroll
            for (int ni = 0; ni < 4; ++ni) {
                int c = cbase + wc + ni * 16 + l15;
                float s = acc[mi][ni][r] * INV_T;
                float e = __expf(s);
                if ((l15 & 7) == cam) pi += e;          // c % 8 == cam
                bool ol = ((c >> 3) == lab);
                bool hard = (!ol) && (c < ((c < lab * 8) ? 50 : 58));
                if (ol || hard) pj += e;
                if (c == oidx) d_own[i] = s;
            }
            #pragma unroll
            for (int off = 1; off < 16; off <<= 1) {
                pi += __shfl_xor(pi, off, 64);
                pj += __shfl_xor(pj, off, 64);
            }
            if (l15 == 0) {
                atomicAdd(&slot_acc[i], pi);
                atomicAdd(&slot_acc[N_SAMP + i], pj);
            }
        }
    }
}

// ---------------- kernel 3: finalize (segment means + output) ----------------
__global__ __launch_bounds__(256) void finalize_kernel(
    const float* __restrict__ d_acc, const float* __restrict__ d_own,
    const int* __restrict__ labels, const int* __restrict__ camids,
    float* __restrict__ out, int out_size)
{
    __shared__ int s_lab[N_SAMP], s_cam[N_SAMP];
    __shared__ float wsum[8];
    int tid = threadIdx.x;
    s_lab[tid] = labels[tid];
    s_cam[tid] = camids[tid];
    __syncthreads();
    int myl = s_lab[tid], myc = s_cam[tid];
    int nl = 0, nc = 0;
    for (int j = 0; j < N_SAMP; ++j) {
        nl += (s_lab[j] == myl);
        nc += (s_cam[j] == myc);
    }
    float di = 0.f, dj = 0.f;
    #pragma unroll
    for (int s = 0; s < 8; ++s) {
        di += d_acc[s * 512 + tid];
        dj += d_acc[s * 512 + 256 + tid];
    }
    float own = d_own[tid];
    float li = own - logf(di);
    float lj = own - logf(dj);
    float a = li / (float)nc;   // sum_i loss_i / n_cam == sum over cams of per-cam mean
    float b = lj / (float)nl;
    #pragma unroll
    for (int off = 1; off < 64; off <<= 1) {
        a += __shfl_xor(a, off, 64);
        b += __shfl_xor(b, off, 64);
    }
    if ((tid & 63) == 0) { wsum[tid >> 6] = a; wsum[4 + (tid >> 6)] = b; }
    __syncthreads();
    if (tid == 0) {
        float sa = wsum[0] + wsum[1] + wsum[2] + wsum[3];
        float sb = wsum[4] + wsum[5] + wsum[6] + wsum[7];
        out[0] = -sa;
        if (out_size > 1) out[1] = -0.5f * sb;   // LAMDA = 0.5
    }
}

extern "C" void kernel_launch(void* const* d_in, const int* in_sizes, int n_in,
                              void* d_out, int out_size, void* d_ws, size_t ws_size,
                              hipStream_t stream) {
    const float* feats   = (const float*)d_in[0];
    const float* centers = (const float*)d_in[1];
    const int*   labels  = (const int*)d_in[2];
    const int*   camids  = (const int*)d_in[3];
    float* out = (float*)d_out;

    char*  fnorm_pk = (char*)d_ws;                                   // 1 MB packed
    float* d_acc    = (float*)((char*)d_ws + (size_t)1048576);       // 8 slots x 512
    float* d_own    = d_acc + 8 * 2 * N_SAMP;                        // 256

    norm_kernel<<<N_SAMP, 256, 0, stream>>>(feats, fnorm_pk, d_acc);
    sims_kernel<<<NWG, 512, 0, stream>>>(fnorm_pk, centers, labels, camids, d_acc, d_own);
    finalize_kernel<<<1, 256, 0, stream>>>(d_acc, d_own, labels, camids, out, out_size);
}